// Round 6
// baseline (869.639 us; speedup 1.0000x reference)
//
#include <hip/hip_runtime.h>
#include <cstdint>
#include <cstddef>

typedef __attribute__((ext_vector_type(8))) short short8;
typedef __attribute__((ext_vector_type(4))) float f32x4;

#define D_MODEL 2048
#define KV_DIM  512
#define N_HEADS 32
#define N_KV    8
#define D_K     64
#define B_SZ    4
#define T_SEQ   2048
#define M_TOT   (B_SZ * T_SEQ)        /* 8192 */
#define N1      (D_MODEL + 2 * KV_DIM) /* 3072 */
#define NEG_BIG (-1e30f)

__device__ __forceinline__ unsigned short f2bf(float f) {
    union { float f; unsigned int i; } c; c.f = f;
    unsigned int u = c.i;
    u += 0x7FFFu + ((u >> 16) & 1u);   // RNE
    return (unsigned short)(u >> 16);
}

// ---------------------------------------------------------------------------
// x (fp32) -> bf16 workspace copy
// ---------------------------------------------------------------------------
__global__ __launch_bounds__(256)
void stage_x(const float* __restrict__ x, unsigned short* __restrict__ xb, int n) {
    for (int i = blockIdx.x * blockDim.x + threadIdx.x; i * 4 < n;
         i += gridDim.x * blockDim.x) {
        const f32x4 v = *(const f32x4*)&x[i * 4];
        unsigned short o[4];
#pragma unroll
        for (int k = 0; k < 4; k++) o[k] = f2bf(v[k]);
        *(uint64_t*)&xb[i * 4] = *(const uint64_t*)o;
    }
}

// ---------------------------------------------------------------------------
// Transpose fp32 src [R][C] -> bf16 dst [C][R]
// ---------------------------------------------------------------------------
__global__ __launch_bounds__(256)
void transpose_f32_bf16(const float* __restrict__ src,
                        unsigned short* __restrict__ dst, int R, int C) {
    __shared__ unsigned short tile[32][34];
    int bx = blockIdx.x * 32;   // col base in src
    int by = blockIdx.y * 32;   // row base in src
    int tx = threadIdx.x;       // 0..31
    int ty = threadIdx.y;       // 0..7
#pragma unroll
    for (int i = 0; i < 32; i += 8)
        tile[ty + i][tx] = f2bf(src[(size_t)(by + ty + i) * C + bx + tx]);
    __syncthreads();
#pragma unroll
    for (int i = 0; i < 32; i += 8)
        dst[(size_t)(bx + ty + i) * R + by + tx] = tile[tx][ty + i];
}

// ---------------------------------------------------------------------------
// GEMM: C[M][N] = A[M][K] * Bt[N][K]^T (+bias fp32), bf16 in, fp32 acc.
// MODE 0: QKV routing epilogue -> bf16 internal buffers (q, k, v^T)
// MODE 1: plain epilogue -> fp32 out
// Tile 128x128, BK=32, 256 threads (4 waves 2x2). (m92-verified pattern)
// ---------------------------------------------------------------------------
template <int MODE>
__global__ __launch_bounds__(256)
void gemm_bt(const unsigned short* __restrict__ A,
             const unsigned short* __restrict__ Bt,
             const float* __restrict__ b0,
             const float* __restrict__ b1,
             const float* __restrict__ b2,
             unsigned short* __restrict__ out0,
             unsigned short* __restrict__ out1,
             unsigned short* __restrict__ out2,
             float* __restrict__ outF,
             int K) {
    __shared__ __align__(16) unsigned short As[128 * 32];
    __shared__ __align__(16) unsigned short Bs[128 * 32];

    const int t    = threadIdx.x;
    const int wave = t >> 6;
    const int lane = t & 63;
    const int quad = lane >> 4;
    const int l16  = lane & 15;
    const int wm   = (wave >> 1) * 64;
    const int wn   = (wave & 1) * 64;
    const int rowBase = blockIdx.y * 128;
    const int colBase = blockIdx.x * 128;

    f32x4 acc[4][4];
#pragma unroll
    for (int i = 0; i < 4; i++)
#pragma unroll
        for (int j = 0; j < 4; j++)
            acc[i][j] = (f32x4){0.f, 0.f, 0.f, 0.f};

    const int r0  = t >> 2;          // 0..63
    const int off = (t & 3) * 8;     // 0,8,16,24
    const unsigned short* Ap = A  + (size_t)(rowBase + r0) * K + off;
    const unsigned short* Bp = Bt + (size_t)(colBase + r0) * K + off;
    const size_t rowStep = (size_t)64 * K;

    for (int k0 = 0; k0 < K; k0 += 32) {
        *(short8*)&As[t * 8]         = *(const short8*)(Ap + k0);
        *(short8*)&As[(t + 256) * 8] = *(const short8*)(Ap + rowStep + k0);
        *(short8*)&Bs[t * 8]         = *(const short8*)(Bp + k0);
        *(short8*)&Bs[(t + 256) * 8] = *(const short8*)(Bp + rowStep + k0);
        __syncthreads();

        short8 af[4], bfr[4];
#pragma unroll
        for (int i = 0; i < 4; i++)
            af[i] = *(const short8*)&As[(wm + i * 16 + l16) * 32 + quad * 8];
#pragma unroll
        for (int i = 0; i < 4; i++)
            bfr[i] = *(const short8*)&Bs[(wn + i * 16 + l16) * 32 + quad * 8];

#pragma unroll
        for (int mi = 0; mi < 4; mi++)
#pragma unroll
            for (int ni = 0; ni < 4; ni++)
                acc[mi][ni] = __builtin_amdgcn_mfma_f32_16x16x32_bf16(
                    af[mi], bfr[ni], acc[mi][ni], 0, 0, 0);
        __syncthreads();
    }

    // Epilogue. Verified C/D layout: col = lane&15, row = quad*4 + reg.
#pragma unroll
    for (int mi = 0; mi < 4; mi++) {
        const int rowT = rowBase + wm + mi * 16 + quad * 4;
#pragma unroll
        for (int ni = 0; ni < 4; ni++) {
            const int col = colBase + wn + ni * 16 + l16;
#pragma unroll
            for (int r = 0; r < 4; r++) {
                float v = acc[mi][ni][r];
                const int rr = rowT + r;
                if (MODE == 0) {
                    if (col < D_MODEL) {
                        v += b0[col];
                        out0[(size_t)rr * D_MODEL + col] = f2bf(v);
                    } else if (col < D_MODEL + KV_DIM) {
                        const int c = col - D_MODEL;
                        v += b1[c];
                        out1[(size_t)rr * KV_DIM + c] = f2bf(v);
                    } else {
                        const int c = col - (D_MODEL + KV_DIM);
                        v += b2[c];
                        const int b   = rr >> 11;       // /2048
                        const int tt  = rr & 2047;
                        const int kvh = c >> 6;
                        const int d   = c & 63;
                        out2[((size_t)((b * N_KV + kvh) * D_K + d)) * T_SEQ + tt] = f2bf(v);
                    }
                } else {
                    v += b0[col];
                    outF[(size_t)rr * D_MODEL + col] = v;   // fp32 final output
                }
            }
        }
    }
}

// ---------------------------------------------------------------------------
// Flash attention (causal, GQA). One block = (b, h, q-tile of 128 rows).
// 4 waves; wave w owns q-rows [w*32, w*32+32). KV tiles of 64.
// LDS: Ks [64][72] | Vs [64][72] | Ps [128][72]; 3 barriers/tile.
// ---------------------------------------------------------------------------
__global__ __launch_bounds__(256)
void attn_fwd(const unsigned short* __restrict__ qb,
              const unsigned short* __restrict__ kb,
              const unsigned short* __restrict__ vt,
              unsigned short* __restrict__ ob) {
    __shared__ __align__(16) unsigned short Ks[64 * 72];
    __shared__ __align__(16) unsigned short Vs[64 * 72];
    __shared__ __align__(16) unsigned short Ps[128 * 72];

    const int t    = threadIdx.x;
    const int wave = t >> 6;
    const int lane = t & 63;
    const int quad = lane >> 4;
    const int l16  = lane & 15;
    const int qt   = blockIdx.x;
    const int h    = blockIdx.y;
    const int b    = blockIdx.z;
    const int kvh  = h >> 2;
    const int qBase = qt * 128;
    const int rowG  = b * T_SEQ;

    short8 qf[2][2];
#pragma unroll
    for (int mi = 0; mi < 2; mi++) {
        const int row = rowG + qBase + wave * 32 + mi * 16 + l16;
#pragma unroll
        for (int kk = 0; kk < 2; kk++)
            qf[mi][kk] = *(const short8*)&qb[(size_t)row * D_MODEL + h * D_K + kk * 32 + quad * 8];
    }

    f32x4 oacc[2][4];
#pragma unroll
    for (int i = 0; i < 2; i++)
#pragma unroll
        for (int j = 0; j < 4; j++)
            oacc[i][j] = (f32x4){0.f, 0.f, 0.f, 0.f};
    float m_run[2][4], l_run[2][4];
#pragma unroll
    for (int i = 0; i < 2; i++)
#pragma unroll
        for (int r = 0; r < 4; r++) { m_run[i][r] = NEG_BIG; l_run[i][r] = 0.f; }

    const float scale = 0.125f;
    const int jMax = 2 * qt + 1;

    for (int j = 0; j <= jMax; ++j) {
        const int sBase = j * 64;
        __syncthreads();  // (A) prior tile fully consumed

#pragma unroll
        for (int i = 0; i < 2; i++) {
            const int c = t + i * 256;
            const int r = c >> 3, o = (c & 7) * 8;
            *(short8*)&Ks[r * 72 + o] =
                *(const short8*)&kb[(size_t)(rowG + sBase + r) * KV_DIM + kvh * D_K + o];
            *(short8*)&Vs[r * 72 + o] =
                *(const short8*)&vt[(size_t)((b * N_KV + kvh) * D_K + r) * T_SEQ + sBase + o];
        }
        __syncthreads();  // (B) staging visible

        f32x4 sacc[2][4];
#pragma unroll
        for (int ni = 0; ni < 4; ni++) {
            const short8 kf0 = *(const short8*)&Ks[(ni * 16 + l16) * 72 + quad * 8];
            const short8 kf1 = *(const short8*)&Ks[(ni * 16 + l16) * 72 + 32 + quad * 8];
#pragma unroll
            for (int mi = 0; mi < 2; mi++) {
                f32x4 s = (f32x4){0.f, 0.f, 0.f, 0.f};
                s = __builtin_amdgcn_mfma_f32_16x16x32_bf16(qf[mi][0], kf0, s, 0, 0, 0);
                s = __builtin_amdgcn_mfma_f32_16x16x32_bf16(qf[mi][1], kf1, s, 0, 0, 0);
                sacc[mi][ni] = s;
            }
        }

        const bool diag = (j >= 2 * qt);
        const int  sRel = sBase - qBase;
#pragma unroll
        for (int mi = 0; mi < 2; mi++) {
            float tm[4];
#pragma unroll
            for (int r = 0; r < 4; r++) tm[r] = NEG_BIG;
#pragma unroll
            for (int ni = 0; ni < 4; ni++) {
#pragma unroll
                for (int r = 0; r < 4; r++) {
                    float v = sacc[mi][ni][r] * scale;
                    if (diag) {
                        const int qrow = wave * 32 + mi * 16 + quad * 4 + r;
                        const int scol = sRel + ni * 16 + l16;
                        if (scol > qrow) v = NEG_BIG;
                    }
                    sacc[mi][ni][r] = v;
                    tm[r] = fmaxf(tm[r], v);
                }
            }
#pragma unroll
            for (int r = 0; r < 4; r++) {
                float v = tm[r];
                v = fmaxf(v, __shfl_xor(v, 1));
                v = fmaxf(v, __shfl_xor(v, 2));
                v = fmaxf(v, __shfl_xor(v, 4));
                v = fmaxf(v, __shfl_xor(v, 8));
                const float mnew  = fmaxf(m_run[mi][r], v);
                const float alpha = __expf(m_run[mi][r] - mnew);
                m_run[mi][r] = mnew;
                l_run[mi][r] *= alpha;
#pragma unroll
                for (int di = 0; di < 4; di++) oacc[mi][di][r] *= alpha;
                float rs = 0.f;
#pragma unroll
                for (int ni = 0; ni < 4; ni++) {
                    const float p = __expf(sacc[mi][ni][r] - mnew);
                    sacc[mi][ni][r] = p;
                    rs += p;
                }
                rs += __shfl_xor(rs, 1);
                rs += __shfl_xor(rs, 2);
                rs += __shfl_xor(rs, 4);
                rs += __shfl_xor(rs, 8);
                l_run[mi][r] += rs;
            }
#pragma unroll
            for (int ni = 0; ni < 4; ni++)
#pragma unroll
                for (int r = 0; r < 4; r++)
                    Ps[(wave * 32 + mi * 16 + quad * 4 + r) * 72 + ni * 16 + l16] =
                        f2bf(sacc[mi][ni][r]);
        }
        __syncthreads();  // (C) Ps visible

#pragma unroll
        for (int ks = 0; ks < 2; ++ks) {
            short8 pa[2];
#pragma unroll
            for (int mi = 0; mi < 2; mi++)
                pa[mi] = *(const short8*)&Ps[(wave * 32 + mi * 16 + l16) * 72 + ks * 32 + quad * 8];
#pragma unroll
            for (int di = 0; di < 4; ++di) {
                const short8 vb = *(const short8*)&Vs[(di * 16 + l16) * 72 + ks * 32 + quad * 8];
#pragma unroll
                for (int mi = 0; mi < 2; mi++)
                    oacc[mi][di] = __builtin_amdgcn_mfma_f32_16x16x32_bf16(
                        pa[mi], vb, oacc[mi][di], 0, 0, 0);
            }
        }
    }

    // Epilogue: normalize and store bf16 (ob aliases qb: own slice only)
#pragma unroll
    for (int mi = 0; mi < 2; mi++) {
#pragma unroll
        for (int r = 0; r < 4; r++) {
            const float inv = 1.f / l_run[mi][r];
            const int row = rowG + qBase + wave * 32 + mi * 16 + quad * 4 + r;
#pragma unroll
            for (int di = 0; di < 4; di++)
                ob[(size_t)row * D_MODEL + h * D_K + di * 16 + l16] =
                    f2bf(oacc[mi][di][r] * inv);
        }
    }
}

// ---------------------------------------------------------------------------
extern "C" void kernel_launch(void* const* d_in, const int* in_sizes, int n_in,
                              void* d_out, int out_size, void* d_ws, size_t ws_size,
                              hipStream_t stream) {
    const float* x  = (const float*)d_in[0];
    const float* Wq = (const float*)d_in[1];
    const float* bq = (const float*)d_in[2];
    const float* Wk = (const float*)d_in[3];
    const float* bk = (const float*)d_in[4];
    const float* Wv = (const float*)d_in[5];
    const float* bv = (const float*)d_in[6];
    const float* Wo = (const float*)d_in[7];
    const float* bo = (const float*)d_in[8];
    float* out = (float*)d_out;

    // Workspace (79,691,776 B; ws_size proven >= 79,691,824):
    //   qb   [0,        33554432)  q bf16 (8192x2048), attn out in place
    //   Wbuf [33554432, 46137344)  W1t (3072x2048 bf16), then Wot
    //   xb   [46137344, 79691776)  x as bf16
    // K and V^T (bf16, 16.8 MB) live at the head of d_out (67 MB fp32 buffer)
    // until gemm2 overwrites d_out with the final fp32 result.
    char* ws = (char*)d_ws;
    unsigned short* qb   = (unsigned short*)(ws);
    unsigned short* Wbuf = (unsigned short*)(ws + 33554432);
    unsigned short* xb   = (unsigned short*)(ws + 46137344);
    unsigned short* kb   = (unsigned short*)d_out;              // 8.4 MB
    unsigned short* vt   = (unsigned short*)d_out + 4194304;    // 8.4 MB

    stage_x<<<4096, 256, 0, stream>>>(x, xb, 16777216);

    dim3 tb(32, 8);
    transpose_f32_bf16<<<dim3(64, 64), tb, 0, stream>>>(Wq, Wbuf, 2048, 2048);
    transpose_f32_bf16<<<dim3(16, 64), tb, 0, stream>>>(Wk, Wbuf + 2048 * 2048, 2048, 512);
    transpose_f32_bf16<<<dim3(16, 64), tb, 0, stream>>>(Wv, Wbuf + 2560 * 2048, 2048, 512);

    gemm_bt<0><<<dim3(N1 / 128, M_TOT / 128), 256, 0, stream>>>(
        xb, Wbuf, bq, bk, bv, qb, kb, vt, nullptr, D_MODEL);

    // W1t no longer needed; stage Wo^T into the same buffer (stream-ordered).
    transpose_f32_bf16<<<dim3(64, 64), tb, 0, stream>>>(Wo, Wbuf, 2048, 2048);

    attn_fwd<<<dim3(T_SEQ / 128, N_HEADS, B_SZ), 256, 0, stream>>>(qb, kb, vt, qb);

    gemm_bt<1><<<dim3(D_MODEL / 128, M_TOT / 128), 256, 0, stream>>>(
        qb, Wbuf, bo, nullptr, nullptr, nullptr, nullptr, nullptr, out, D_MODEL);
}